// Round 5
// baseline (204.297 us; speedup 1.0000x reference)
//
#include <hip/hip_runtime.h>

// DynamicRouting: grouped 1x1 conv (einsum bgihw,gfi->bgfhw) + 3-iter routing.
// B=16, G=8, FI=FO=64, HW=4096. Fully fused: con never touches HBM.
//
// R9: occupancy attack. R7/R8 counters: Occ 20% (2 waves/SIMD, VGPR 216 ->
// 129-256 bucket -> 8 waves/CU), all pipes idle, and depth-2->3 prefetch was
// a null => issue-side latency, needs TLP not more ILP. R9 splits the f
// (output-channel) dimension across waves: 512-thread blocks, 8 waves =
// 4 pixel-slices x 2 f-halves; acc[8][2] = 64 VGPR/lane. launch_bounds(512,4)
// caps at 128 VGPR -> 65-128 bucket -> 16 waves/CU (2 blocks x 8 waves, LDS
// 80 KB unchanged). Staging re-divided: w 8 floats/wave (h AND l from same
// octet, 2 dwordx4), x 2x1KB global_load_lds/wave; steady vmcnt(6) (retire
// X(g),W(g), keep X(g+1),W(g+1),X(g+2)), tail vmcnt(4)/vmcnt(0). Routing
// f-sums now span 2 waves -> per-iter 4 KB LDS exchange overlaid on dead
// xlds[2] (LDS stays 80 KB), 3 extra syncthreads. Conv math bit-identical;
// beta re-associated (own+partner, commutative) - inside 0.125 threshold.

typedef __attribute__((ext_vector_type(8))) _Float16 half8;
typedef __attribute__((ext_vector_type(4))) float f32x4;

#define NG   8
#define NFI  64
#define NFO  64
#define HW   4096

__device__ __forceinline__ float sigmoidf_fast(float v) {
    float e = __builtin_amdgcn_exp2f(-1.44269504088896f * v);
    return __builtin_amdgcn_rcpf(1.0f + e);
}

// ---- fused conv + routing: 8 waves, f-split acc, depth-3 x pipeline ----
__global__ __launch_bounds__(512, 4)
void routing_kernel(const float* __restrict__ x,
                    const float* __restrict__ w,
                    const float* __restrict__ bias,
                    float* __restrict__ out) {
    const int tid  = threadIdx.x;
    const int b    = blockIdx.x >> 6;          // batch
    const int p0   = (blockIdx.x & 63) << 6;   // pixel tile base
    const int lane = tid & 63;
    const int wv   = tid >> 6;                 // wave 0..7
    const int ps   = wv & 3;                   // pixel slice (16 px)
    const int fh   = wv >> 2;                  // f-half: t in {2fh, 2fh+1}
    const int pl   = lane & 15;                // MFMA n-lane (pixel)
    const int q    = lane >> 4;                // k-octet select / C row group
    const int pw   = ps * 16 + pl;             // pixel within tile

    // triple-buffered x tiles (64ch x 64px fp32 = 16 KB), double-buffered w.
    // Total 80 KB -> 2 blocks/CU. xlds[2] is reused as the routing exchange
    // buffer after the main loop (it is dead after XGRP(5) + barriers).
    __shared__ float    xlds[3][64 * 64];
    __shared__ _Float16 wlds[2][16 * 512];

    const float* xbase = x + (size_t)b * (NG * NFI) * HW;

    // w staging role (independent of compute role): t_s = wv>>1, kh = wv&1.
    // Each wave loads 8 floats/group (rows t_s*16+pl, k = kh*32+q*8..+8) and
    // produces BOTH the h row (c=kh) and l row (c=2+kh) of the fragment
    // layout. Conversion math bit-identical to R8's WCONV.
    const int t_s = wv >> 1, kh = wv & 1;
    const float* wsrc = w + (size_t)(t_s * 16 + pl) * NFI + kh * 32 + q * 8;

    // x staging: wave covers rows [8wv, 8wv+8), 2 instrs (c=0,1), 4 rows each.
    // Rotation swizzle on the GLOBAL source (LDS dest linear):
    // LDS[ch*64 + s] holds pixel p = (s - 8*(ch>>3)) & 63.
#define MKXS(c) \
    const int   ch##c = wv * 8 + (c) * 4 + q; \
    const float* xs##c = xbase + (size_t)ch##c * HW + p0 + ((pl * 4 - 8 * (ch##c >> 3)) & 63);
    MKXS(0) MKXS(1)
#undef MKXS

    // b-frag read bases (floats, within a 16 KB x tile):
    //   b0 row ch=q*8+j  : slot=(pw+8q)&63,    + j*64
    //   b1 row ch=32+q*8+j: slot=(pw+8q+32)&63, + j*64
    // bank = (pl + 8q + 16ps) mod 32 -> exactly 2 lanes/bank (free).
    const int rb0 = q * 512 + ((pw + 8 * q) & 63);
    const int rb1 = 2048 + q * 512 + ((pw + 8 * q + 32) & 63);

    f32x4 acc[NG][2];
    #pragma unroll
    for (int g = 0; g < NG; ++g)
        #pragma unroll
        for (int tt = 0; tt < 2; ++tt)
            acc[g][tt] = (f32x4){0.f, 0.f, 0.f, 0.f};

#define CB    asm volatile("" ::: "memory")
#define BAR   __builtin_amdgcn_s_barrier()
#define SB0   __builtin_amdgcn_sched_barrier(0)
#define WAITV(N) asm volatile("s_waitcnt vmcnt(" #N ")" ::: "memory")
#define LGKM0 asm volatile("s_waitcnt lgkmcnt(0)" ::: "memory")

    // load group G's 8 raw fp32 weights for this thread (2 x dwordx4)
#define WLOAD(G, NM)                                                          \
    NM##a = *(const f32x4*)(wsrc + (size_t)(G) * 4096);                       \
    NM##b = *(const f32x4*)(wsrc + (size_t)(G) * 4096 + 4);

    // convert octet to h row (c=kh) and l row (c=2+kh) of wlds[(G)&1]
#define WCONV(G, NM)                                                          \
    {                                                                         \
        half8 hh_, ll_;                                                       \
        _Pragma("unroll")                                                     \
        for (int j = 0; j < 4; ++j) {                                         \
            float f0 = NM##a[j], f1 = NM##b[j];                               \
            _Float16 e0 = (_Float16)f0, e1 = (_Float16)f1;                    \
            hh_[j] = e0; hh_[j + 4] = e1;                                     \
            ll_[j]     = (_Float16)(f0 - (float)e0);                          \
            ll_[j + 4] = (_Float16)(f1 - (float)e1);                          \
        }                                                                     \
        _Float16* wd_ = &wlds[(G) & 1][0] + (t_s * 4 + kh) * 512 + lane * 8;  \
        *(half8*)(wd_)        = hh_;                                          \
        *(half8*)(wd_ + 1024) = ll_;                                          \
    }

    // stage group G's x rows [8wv, 8wv+8): 2 x 1 KB global_load_lds
#define XSTAGE(G, BUF)                                                        \
    {                                                                         \
        const size_t go_ = (size_t)(G) * 64 * HW;                             \
        float* xd_ = &xlds[BUF][0] + (wv * 8) * 64;                           \
        __builtin_amdgcn_global_load_lds(                                     \
            (const __attribute__((address_space(1))) void*)(xs0 + go_),       \
            (__attribute__((address_space(3))) void*)(xd_), 16, 0, 0);        \
        __builtin_amdgcn_global_load_lds(                                     \
            (const __attribute__((address_space(1))) void*)(xs1 + go_),       \
            (__attribute__((address_space(3))) void*)(xd_ + 256), 16, 0, 0);  \
    }

    // consume group G: b-frags from xlds[BUF], a-frags for own 2 t-rows
#define XGRP(G, BUF)                                                         \
    {                                                                        \
        const float* xr0_ = &xlds[BUF][0] + rb0;                             \
        const float* xr1_ = &xlds[BUF][0] + rb1;                             \
        half8 b0, b1;                                                        \
        b0[0] = (_Float16)xr0_[0 * 64]; b0[1] = (_Float16)xr0_[1 * 64];      \
        b0[2] = (_Float16)xr0_[2 * 64]; b0[3] = (_Float16)xr0_[3 * 64];      \
        b0[4] = (_Float16)xr0_[4 * 64]; b0[5] = (_Float16)xr0_[5 * 64];      \
        b0[6] = (_Float16)xr0_[6 * 64]; b0[7] = (_Float16)xr0_[7 * 64];      \
        b1[0] = (_Float16)xr1_[0 * 64]; b1[1] = (_Float16)xr1_[1 * 64];      \
        b1[2] = (_Float16)xr1_[2 * 64]; b1[3] = (_Float16)xr1_[3 * 64];      \
        b1[4] = (_Float16)xr1_[4 * 64]; b1[5] = (_Float16)xr1_[5 * 64];      \
        b1[6] = (_Float16)xr1_[6 * 64]; b1[7] = (_Float16)xr1_[7 * 64];      \
        const _Float16* wg_ = &wlds[(G) & 1][0] + lane * 8;                  \
        _Pragma("unroll")                                                    \
        for (int tt = 0; tt < 2; ++tt) {                                     \
            const _Float16* wp_ = wg_ + (size_t)(fh * 2 + tt) * 2048;        \
            half8 a0h = *(const half8*)(wp_);                                \
            half8 a1h = *(const half8*)(wp_ + 512);                          \
            half8 a0l = *(const half8*)(wp_ + 1024);                         \
            half8 a1l = *(const half8*)(wp_ + 1536);                         \
            acc[G][tt] = __builtin_amdgcn_mfma_f32_16x16x32_f16(a0h, b0, acc[G][tt], 0, 0, 0); \
            acc[G][tt] = __builtin_amdgcn_mfma_f32_16x16x32_f16(a1h, b1, acc[G][tt], 0, 0, 0); \
            acc[G][tt] = __builtin_amdgcn_mfma_f32_16x16x32_f16(a0l, b0, acc[G][tt], 0, 0, 0); \
            acc[G][tt] = __builtin_amdgcn_mfma_f32_16x16x32_f16(a1l, b1, acc[G][tt], 0, 0, 0); \
        }                                                                    \
    }

    f32x4 Waa, Wab;   // w fp32 octet, even groups
    f32x4 Wba, Wbb;   // w fp32 octet, odd groups

    // Prologue FIFO: W0(2) X0(2) W1(2) X1(2) X2(2) -- 10 in flight
    WLOAD(0, Wa) CB; XSTAGE(0, 0); CB;
    WLOAD(1, Wb) CB; XSTAGE(1, 1); CB;
    XSTAGE(2, 2); CB;

    // Steady step g: [vmcnt(6): retire X(g),W(g); keep {X(g+1),W(g+1),X(g+2)}]
    // [convert+ds_write w(g)] [lgkmcnt(0)] [barrier] [compute g] [barrier]
    // [issue W(g+2), X(g+3) into freed x buffer].
    WAITV(6); WCONV(0, Wa) LGKM0; BAR; SB0; XGRP(0, 0); BAR; WLOAD(2, Wa) CB; XSTAGE(3, 0); CB;
    WAITV(6); WCONV(1, Wb) LGKM0; BAR; SB0; XGRP(1, 1); BAR; WLOAD(3, Wb) CB; XSTAGE(4, 1); CB;
    WAITV(6); WCONV(2, Wa) LGKM0; BAR; SB0; XGRP(2, 2); BAR; WLOAD(4, Wa) CB; XSTAGE(5, 2); CB;
    WAITV(6); WCONV(3, Wb) LGKM0; BAR; SB0; XGRP(3, 0); BAR; WLOAD(5, Wb) CB; XSTAGE(6, 0); CB;
    WAITV(6); WCONV(4, Wa) LGKM0; BAR; SB0; XGRP(4, 1); BAR; WLOAD(6, Wa) CB; XSTAGE(7, 1); CB;
    WAITV(6); WCONV(5, Wb) LGKM0; BAR; SB0; XGRP(5, 2); BAR; WLOAD(7, Wb) CB;
    WAITV(4); WCONV(6, Wa) LGKM0; BAR; SB0; XGRP(6, 0); BAR;
    WAITV(0); WCONV(7, Wb) LGKM0; BAR; SB0; XGRP(7, 1);

#undef XGRP
#undef XSTAGE
#undef WCONV
#undef WLOAD
#undef CB
#undef BAR
#undef SB0
#undef WAITV
#undef LGKM0

    // ---- routing (fp32, per pixel), f = (fh*2+tt)*16 + q*4 + r ----
    // Per-pixel f-sums span the two fh waves -> LDS exchange via bex
    // (overlaid on xlds[2]; dead since XGRP(5), separated by 4 barriers).
    float* bex = (float*)&xlds[2][0];   // [wv][g][pl] = wv*128 + g*16 + pl

    // iter 0: v0[f] = 0.5*sum_g con ; beta1[g] = sum_f v0*con
    float v0[2][4];
    #pragma unroll
    for (int tt = 0; tt < 2; ++tt)
        #pragma unroll
        for (int r = 0; r < 4; ++r) {
            float s = 0.f;
            #pragma unroll
            for (int g = 0; g < NG; ++g) s += acc[g][tt][r];
            v0[tt][r] = 0.5f * s;
        }

    float sg[NG];
    #pragma unroll
    for (int g = 0; g < NG; ++g) {
        float s = 0.f;
        #pragma unroll
        for (int tt = 0; tt < 2; ++tt)
            #pragma unroll
            for (int r = 0; r < 4; ++r)
                s += v0[tt][r] * acc[g][tt][r];
        s += __shfl_xor(s, 16);   // close q-sum (32 f's of this fh)
        s += __shfl_xor(s, 32);
        sg[g] = s;
    }
    if (q == 0) {
        #pragma unroll
        for (int g = 0; g < NG; ++g) bex[wv * 128 + g * 16 + pl] = sg[g];
    }
    __syncthreads();
    float beta[NG], alpha[NG];
    #pragma unroll
    for (int g = 0; g < NG; ++g) {
        float s = sg[g] + bex[(wv ^ 4) * 128 + g * 16 + pl];
        beta[g]  = s;
        alpha[g] = sigmoidf_fast(s);
    }

    // iter 1: v1[f] = sum_g alpha*con ; beta2 = beta1 + sum_f v1*con
    #pragma unroll
    for (int tt = 0; tt < 2; ++tt)
        #pragma unroll
        for (int r = 0; r < 4; ++r) {
            float s = 0.f;
            #pragma unroll
            for (int g = 0; g < NG; ++g) s += alpha[g] * acc[g][tt][r];
            v0[tt][r] = s;  // reuse as v1
        }
    #pragma unroll
    for (int g = 0; g < NG; ++g) {
        float s = 0.f;
        #pragma unroll
        for (int tt = 0; tt < 2; ++tt)
            #pragma unroll
            for (int r = 0; r < 4; ++r)
                s += v0[tt][r] * acc[g][tt][r];
        s += __shfl_xor(s, 16);
        s += __shfl_xor(s, 32);
        sg[g] = s;
    }
    __syncthreads();   // iter-0 reads of bex complete before overwrite
    if (q == 0) {
        #pragma unroll
        for (int g = 0; g < NG; ++g) bex[wv * 128 + g * 16 + pl] = sg[g];
    }
    __syncthreads();
    #pragma unroll
    for (int g = 0; g < NG; ++g) {
        float s = sg[g] + bex[(wv ^ 4) * 128 + g * 16 + pl];
        beta[g] += s;
        alpha[g] = sigmoidf_fast(beta[g]);
    }

    // iter 2: out[f] = sum_g alpha2*con + bias[f]  (own 2 t-rows)
    #pragma unroll
    for (int tt = 0; tt < 2; ++tt)
        #pragma unroll
        for (int r = 0; r < 4; ++r) {
            int f = (fh * 2 + tt) * 16 + q * 4 + r;
            float s = bias[f];
            #pragma unroll
            for (int g = 0; g < NG; ++g) s += alpha[g] * acc[g][tt][r];
            out[((size_t)(b * NFO + f)) * HW + p0 + pw] = s;
        }
}

extern "C" void kernel_launch(void* const* d_in, const int* in_sizes, int n_in,
                              void* d_out, int out_size, void* d_ws, size_t ws_size,
                              hipStream_t stream) {
    const float* x    = (const float*)d_in[0];
    const float* w    = (const float*)d_in[1];
    const float* bias = (const float*)d_in[2];
    float* out = (float*)d_out;
    (void)d_ws; (void)ws_size;   // workspace unused

    routing_kernel<<<1024, 512, 0, stream>>>(x, w, bias, out);
}

// Round 6
// 200.328 us; speedup vs baseline: 1.0198x; 1.0198x over previous
//
#include <hip/hip_runtime.h>

// DynamicRouting: grouped 1x1 conv (einsum bgihw,gfi->bgfhw) + 3-iter routing.
// B=16, G=8, FI=FO=64, HW=4096. Fully fused: con never touches HBM.
//
// R10: revert to R7 (best measured: 201.16 us) after R8 (depth-3 prefetch)
// and R9 (2x occupancy via f-split) both returned null-to-negative - three
// orthogonal structural levers inside +-1.5% => kernel is at its floor and
// mostly off the timed critical path (156 us of the ~201 is two 512-MiB
// harness poison fills at 86% of achievable BW). Single change vs R7: the
// epilogue out-stores are __builtin_nontemporal_store (out is write-once,
// never re-read; keeping its 17 MB out of L2/L3 preserves x residency during
// the kernel and across iterations). Stored values identical -> absmax 0.125.

typedef __attribute__((ext_vector_type(8))) _Float16 half8;
typedef __attribute__((ext_vector_type(4))) float f32x4;

#define NG   8
#define NFI  64
#define NFO  64
#define HW   4096

__device__ __forceinline__ float sigmoidf_fast(float v) {
    float e = __builtin_amdgcn_exp2f(-1.44269504088896f * v);
    return __builtin_amdgcn_rcpf(1.0f + e);
}

// ---- fused conv + routing: LDS-staged x AND w, depth-2 pipeline ----
__global__ __launch_bounds__(256, 2)
void routing_kernel(const float* __restrict__ x,
                    const float* __restrict__ w,
                    const float* __restrict__ bias,
                    float* __restrict__ out) {
    const int tid  = threadIdx.x;
    const int b    = blockIdx.x >> 6;          // batch
    const int p0   = (blockIdx.x & 63) << 6;   // pixel tile base
    const int lane = tid & 63;
    const int wv   = tid >> 6;                 // wave -> 16-px slice / w t-row
    const int pl   = lane & 15;                // MFMA n-lane (pixel)
    const int q    = lane >> 4;                // k-octet select / C row group
    const int pw   = wv * 16 + pl;             // pixel within tile

    // double-buffered tiles: x = 64ch x 64px fp32 (16 KB), w = 16 KB fp16
    __shared__ float    xlds[2][64 * 64];
    __shared__ _Float16 wlds[2][16 * 512];

    const float* xbase = x + (size_t)b * (NG * NFI) * HW;

    // w source for this thread's fragments: row t=wv*16+pl, k-octet q*8 (+32
    // for the upper k-half). Group g adds g*4096 floats. 16 B aligned.
    const float* wsrc = w + (size_t)(wv * 16 + pl) * NFI + q * 8;

    // per-lane X-stage source pointers. Stage instr c: wave writes LDS floats
    // [(wv*16 + c*4)*64, +256) linearly (lane i -> +i*4 floats). Lane covers
    // ch = wv*16 + c*4 + (lane>>4), slots pl*4..pl*4+3. Rotation swizzle:
    // LDS[ch*64 + s] holds pixel p = (s - 8*(ch>>3)) & 63, so the global
    // source is pre-rotated; runs of 4 slots map to contiguous 4-px runs.
#define MKXS(c) \
    const int   ch##c = wv * 16 + (c) * 4 + q; \
    const float* xs##c = xbase + (size_t)ch##c * HW + p0 + ((pl * 4 - 8 * (ch##c >> 3)) & 63);
    MKXS(0) MKXS(1) MKXS(2) MKXS(3)
#undef MKXS

    // b-frag read bases (floats, within a 16 KB x tile):
    //   b0 row ch=q*8+j  : rot=8q    -> slot=(pw+8q)&63,    + j*64
    //   b1 row ch=32+q*8+j: rot=32+8q -> slot=(pw+8q+32)&63, + j*64
    // bank = (pl + 8q + 16wv) mod 32 -> exactly 2 lanes/bank (free).
    const int rb0 = q * 512 + ((pw + 8 * q) & 63);
    const int rb1 = 2048 + q * 512 + ((pw + 8 * q + 32) & 63);

    f32x4 acc[NG][4];
    #pragma unroll
    for (int g = 0; g < NG; ++g)
        #pragma unroll
        for (int t = 0; t < 4; ++t)
            acc[g][t] = (f32x4){0.f, 0.f, 0.f, 0.f};

#define CB    asm volatile("" ::: "memory")
#define BAR   __builtin_amdgcn_s_barrier()
#define SB0   __builtin_amdgcn_sched_barrier(0)
#define WAITV(N) asm volatile("s_waitcnt vmcnt(" #N ")" ::: "memory")
#define LGKM0 asm volatile("s_waitcnt lgkmcnt(0)" ::: "memory")

    // load group G's raw fp32 weight octets for this thread (4 x dwordx4)
#define WLOAD(G, NM)                                                          \
    NM##a = *(const f32x4*)(wsrc + (size_t)(G) * 4096);                       \
    NM##b = *(const f32x4*)(wsrc + (size_t)(G) * 4096 + 4);                   \
    NM##c = *(const f32x4*)(wsrc + (size_t)(G) * 4096 + 32);                  \
    NM##d = *(const f32x4*)(wsrc + (size_t)(G) * 4096 + 36);

    // convert to h/l fp16 split (bit-identical to old wconv) and write the
    // fragment-ordered rows t=wv, c=0..3 into wlds[(G)&1]. Each ds_write_b128
    // has lanes at consecutive 16 B -> conflict-free.
#define WCONV(G, NM)                                                          \
    {                                                                         \
        half8 h0_, h1_, l0_, l1_;                                             \
        _Pragma("unroll")                                                     \
        for (int j = 0; j < 4; ++j) {                                         \
            float f0 = NM##a[j], f1 = NM##b[j], f2 = NM##c[j], f3 = NM##d[j]; \
            _Float16 e0 = (_Float16)f0, e1 = (_Float16)f1;                    \
            _Float16 e2 = (_Float16)f2, e3 = (_Float16)f3;                    \
            h0_[j] = e0; h0_[j + 4] = e1;                                     \
            h1_[j] = e2; h1_[j + 4] = e3;                                     \
            l0_[j]     = (_Float16)(f0 - (float)e0);                          \
            l0_[j + 4] = (_Float16)(f1 - (float)e1);                          \
            l1_[j]     = (_Float16)(f2 - (float)e2);                          \
            l1_[j + 4] = (_Float16)(f3 - (float)e3);                          \
        }                                                                     \
        _Float16* wd_ = &wlds[(G) & 1][0] + (wv * 4) * 512 + lane * 8;        \
        *(half8*)(wd_)        = h0_;                                          \
        *(half8*)(wd_ + 512)  = h1_;                                          \
        *(half8*)(wd_ + 1024) = l0_;                                          \
        *(half8*)(wd_ + 1536) = l1_;                                          \
    }

    // stage group G's 16 KB x tile: 4 x 1 KB global_load_lds per wave
#define XSTAGE(G, BUF)                                                        \
    {                                                                         \
        const size_t go_ = (size_t)(G) * 64 * HW;                             \
        float* xd_ = &xlds[BUF][0] + (wv * 16) * 64;                          \
        __builtin_amdgcn_global_load_lds(                                     \
            (const __attribute__((address_space(1))) void*)(xs0 + go_),       \
            (__attribute__((address_space(3))) void*)(xd_), 16, 0, 0);        \
        __builtin_amdgcn_global_load_lds(                                     \
            (const __attribute__((address_space(1))) void*)(xs1 + go_),       \
            (__attribute__((address_space(3))) void*)(xd_ + 256), 16, 0, 0);  \
        __builtin_amdgcn_global_load_lds(                                     \
            (const __attribute__((address_space(1))) void*)(xs2 + go_),       \
            (__attribute__((address_space(3))) void*)(xd_ + 512), 16, 0, 0);  \
        __builtin_amdgcn_global_load_lds(                                     \
            (const __attribute__((address_space(1))) void*)(xs3 + go_),       \
            (__attribute__((address_space(3))) void*)(xd_ + 768), 16, 0, 0);  \
    }

    // consume group G from buffer BUF: b-frags from xlds, a-frags from wlds
#define XGRP(G, BUF)                                                         \
    {                                                                        \
        const float* xr0_ = &xlds[BUF][0] + rb0;                             \
        const float* xr1_ = &xlds[BUF][0] + rb1;                             \
        half8 b0, b1;                                                        \
        b0[0] = (_Float16)xr0_[0 * 64]; b0[1] = (_Float16)xr0_[1 * 64];      \
        b0[2] = (_Float16)xr0_[2 * 64]; b0[3] = (_Float16)xr0_[3 * 64];      \
        b0[4] = (_Float16)xr0_[4 * 64]; b0[5] = (_Float16)xr0_[5 * 64];      \
        b0[6] = (_Float16)xr0_[6 * 64]; b0[7] = (_Float16)xr0_[7 * 64];      \
        b1[0] = (_Float16)xr1_[0 * 64]; b1[1] = (_Float16)xr1_[1 * 64];      \
        b1[2] = (_Float16)xr1_[2 * 64]; b1[3] = (_Float16)xr1_[3 * 64];      \
        b1[4] = (_Float16)xr1_[4 * 64]; b1[5] = (_Float16)xr1_[5 * 64];      \
        b1[6] = (_Float16)xr1_[6 * 64]; b1[7] = (_Float16)xr1_[7 * 64];      \
        const _Float16* wg_ = &wlds[BUF][0] + lane * 8;                      \
        _Pragma("unroll")                                                    \
        for (int t = 0; t < 4; ++t) {                                        \
            const _Float16* wp_ = wg_ + (size_t)t * 2048;                    \
            half8 a0h = *(const half8*)(wp_);                                \
            half8 a1h = *(const half8*)(wp_ + 512);                          \
            half8 a0l = *(const half8*)(wp_ + 1024);                         \
            half8 a1l = *(const half8*)(wp_ + 1536);                         \
            acc[G][t] = __builtin_amdgcn_mfma_f32_16x16x32_f16(a0h, b0, acc[G][t], 0, 0, 0); \
            acc[G][t] = __builtin_amdgcn_mfma_f32_16x16x32_f16(a1h, b1, acc[G][t], 0, 0, 0); \
            acc[G][t] = __builtin_amdgcn_mfma_f32_16x16x32_f16(a0l, b0, acc[G][t], 0, 0, 0); \
            acc[G][t] = __builtin_amdgcn_mfma_f32_16x16x32_f16(a1l, b1, acc[G][t], 0, 0, 0); \
        }                                                                    \
    }

    f32x4 Waa, Wab, Wac, Wad;   // w fp32 regs, even groups
    f32x4 Wba, Wbb, Wbc, Wbd;   // w fp32 regs, odd groups

    // Prologue FIFO: W0(4) X0(4) W1(4) X1(4)  -- 16 vmem instrs/wave in flight
    WLOAD(0, Wa) CB; XSTAGE(0, 0); CB;
    WLOAD(1, Wb) CB; XSTAGE(1, 1); CB;

    // Steady step g: [vmcnt(8): W(g) regs + X(g) LDS arrived, W(g+1)/X(g+1)
    // stay in flight] [convert+ds_write w(g)] [lgkmcnt(0): writes visible]
    // [barrier] [compute g] [barrier: bufs free] [issue W(g+2), X(g+2)].
    WAITV(8); WCONV(0, Wa) LGKM0; BAR; SB0; XGRP(0, 0); BAR; WLOAD(2, Wa) CB; XSTAGE(2, 0); CB;
    WAITV(8); WCONV(1, Wb) LGKM0; BAR; SB0; XGRP(1, 1); BAR; WLOAD(3, Wb) CB; XSTAGE(3, 1); CB;
    WAITV(8); WCONV(2, Wa) LGKM0; BAR; SB0; XGRP(2, 0); BAR; WLOAD(4, Wa) CB; XSTAGE(4, 0); CB;
    WAITV(8); WCONV(3, Wb) LGKM0; BAR; SB0; XGRP(3, 1); BAR; WLOAD(5, Wb) CB; XSTAGE(5, 1); CB;
    WAITV(8); WCONV(4, Wa) LGKM0; BAR; SB0; XGRP(4, 0); BAR; WLOAD(6, Wa) CB; XSTAGE(6, 0); CB;
    WAITV(8); WCONV(5, Wb) LGKM0; BAR; SB0; XGRP(5, 1); BAR; WLOAD(7, Wb) CB; XSTAGE(7, 1); CB;
    WAITV(8); WCONV(6, Wa) LGKM0; BAR; SB0; XGRP(6, 0); BAR;
    WAITV(0); WCONV(7, Wb) LGKM0; BAR; SB0; XGRP(7, 1);

#undef XGRP
#undef XSTAGE
#undef WCONV
#undef WLOAD
#undef CB
#undef BAR
#undef SB0
#undef WAITV
#undef LGKM0

    // ---- routing (all fp32, per pixel), f = t*16 + q*4 + r ----
    // iter 0: v0[f] = 0.5*sum_g con ; beta1[g] = sum_f v0*con
    float v0[4][4];
    #pragma unroll
    for (int t = 0; t < 4; ++t)
        #pragma unroll
        for (int r = 0; r < 4; ++r) {
            float s = 0.f;
            #pragma unroll
            for (int g = 0; g < NG; ++g) s += acc[g][t][r];
            v0[t][r] = 0.5f * s;
        }

    float beta[NG], alpha[NG];
    #pragma unroll
    for (int g = 0; g < NG; ++g) {
        float s = 0.f;
        #pragma unroll
        for (int t = 0; t < 4; ++t)
            #pragma unroll
            for (int r = 0; r < 4; ++r)
                s += v0[t][r] * acc[g][t][r];
        s += __shfl_xor(s, 16);   // close f-sum across the 4 q-lanes
        s += __shfl_xor(s, 32);
        beta[g]  = s;
        alpha[g] = sigmoidf_fast(s);
    }

    // iter 1: v1[f] = sum_g alpha*con ; beta2 = beta1 + sum_f v1*con
    #pragma unroll
    for (int t = 0; t < 4; ++t)
        #pragma unroll
        for (int r = 0; r < 4; ++r) {
            float s = 0.f;
            #pragma unroll
            for (int g = 0; g < NG; ++g) s += alpha[g] * acc[g][t][r];
            v0[t][r] = s;  // reuse as v1
        }
    #pragma unroll
    for (int g = 0; g < NG; ++g) {
        float s = 0.f;
        #pragma unroll
        for (int t = 0; t < 4; ++t)
            #pragma unroll
            for (int r = 0; r < 4; ++r)
                s += v0[t][r] * acc[g][t][r];
        s += __shfl_xor(s, 16);
        s += __shfl_xor(s, 32);
        beta[g] += s;
        alpha[g] = sigmoidf_fast(beta[g]);
    }

    // iter 2: out[f] = sum_g alpha2*con + bias[f] -- nontemporal (write-once,
    // never re-read: keep out of L2/L3 so x residency survives)
    #pragma unroll
    for (int t = 0; t < 4; ++t)
        #pragma unroll
        for (int r = 0; r < 4; ++r) {
            int f = t * 16 + q * 4 + r;
            float s = bias[f];
            #pragma unroll
            for (int g = 0; g < NG; ++g) s += alpha[g] * acc[g][t][r];
            __builtin_nontemporal_store(
                s, &out[((size_t)(b * NFO + f)) * HW + p0 + pw]);
        }
}

extern "C" void kernel_launch(void* const* d_in, const int* in_sizes, int n_in,
                              void* d_out, int out_size, void* d_ws, size_t ws_size,
                              hipStream_t stream) {
    const float* x    = (const float*)d_in[0];
    const float* w    = (const float*)d_in[1];
    const float* bias = (const float*)d_in[2];
    float* out = (float*)d_out;
    (void)d_ws; (void)ws_size;   // workspace unused

    routing_kernel<<<1024, 256, 0, stream>>>(x, w, bias, out);
}